// Round 1
// baseline (1711.527 us; speedup 1.0000x reference)
//
#include <hip/hip_runtime.h>

#define N_NODES 200000
#define N_EDGES 1250000
#define N_GRAPHS 2048

// ---------------- degree ----------------
__global__ void init_deg(float* dis) {
    int i = blockIdx.x * blockDim.x + threadIdx.x;
    if (i < N_NODES) dis[i] = 1.0f;   // self-loop contributes 1
}

__global__ void count_deg(const int* __restrict__ ei, float* dis) {
    int e = blockIdx.x * blockDim.x + threadIdx.x;
    if (e < N_EDGES) atomicAdd(&dis[ei[N_EDGES + e]], 1.0f);  // dst row
}

__global__ void finalize_deg(float* dis) {
    int i = blockIdx.x * blockDim.x + threadIdx.x;
    if (i < N_NODES) dis[i] = rsqrtf(dis[i]);  // deg >= 1 always
}

// ---------------- dense GEMM: Out[n][m] = sum_k X[n][k] * W[k][m] ----------------
template<int K, int M>
__global__ void gemm_kernel(const float* __restrict__ X, const float* __restrict__ W,
                            float* __restrict__ Out, int n) {
    __shared__ float Wl[K * M];
    for (int t = threadIdx.x; t < K * M; t += 256) Wl[t] = W[t];
    __syncthreads();
    constexpr int ROWS = 256 / M;
    int row = blockIdx.x * ROWS + (int)(threadIdx.x / M);
    int col = threadIdx.x % M;
    if (row >= n) return;
    const float* xr = X + (size_t)row * K;
    float acc = 0.f;
#pragma unroll 8
    for (int k = 0; k < K; ++k) acc += xr[k] * Wl[k * M + col];
    Out[(size_t)row * M + col] = acc;
}

// ---------------- edge scatter: Agg[dst] += dis[src]*dis[dst]*H[src] ----------------
template<int C>
__global__ void scatter_kernel(const float* __restrict__ H, const float* __restrict__ dis,
                               const int* __restrict__ ei, float* __restrict__ Agg) {
    unsigned int t = blockIdx.x * blockDim.x + threadIdx.x;
    if (t >= (unsigned int)N_EDGES * C) return;
    unsigned int e = t / C;
    unsigned int c = t % C;
    int s = ei[e];
    int d = ei[N_EDGES + e];
    float norm = dis[s] * dis[d];
    atomicAdd(&Agg[(size_t)d * C + c], norm * H[(size_t)s * C + c]);
}

// ---------------- self-loop + bias + relu ----------------
template<int C>
__global__ void finalize_kernel(float* __restrict__ Agg, const float* __restrict__ H,
                                const float* __restrict__ dis, const float* __restrict__ b) {
    int t = blockIdx.x * blockDim.x + threadIdx.x;
    if (t >= N_NODES * C) return;
    int n = t / C, c = t % C;
    float ds = dis[n];
    float v = Agg[t] + ds * ds * H[t] + b[c];
    Agg[t] = fmaxf(v, 0.f);
}

// ---------------- global mean pool (phase 1: sums + counts) ----------------
__global__ void pool_kernel(const float* __restrict__ H, const int* __restrict__ batch,
                            float* __restrict__ sums, float* __restrict__ cnt) {
    int t = blockIdx.x * blockDim.x + threadIdx.x;
    if (t >= N_NODES * 32) return;
    int n = t >> 5, c = t & 31;
    int g = batch[n];
    atomicAdd(&sums[g * 32 + c], H[t]);
    if (c == 0) atomicAdd(&cnt[g], 1.0f);
}

// ---------------- classifier MLP: one thread per graph ----------------
__global__ void classifier_kernel(const float* __restrict__ sums, const float* __restrict__ cnt,
                                  const float* __restrict__ Wc1, const float* __restrict__ bc1,
                                  const float* __restrict__ Wc2, const float* __restrict__ bc2,
                                  float* __restrict__ out) {
    int g = blockIdx.x * blockDim.x + threadIdx.x;
    if (g >= N_GRAPHS) return;
    float inv = 1.0f / fmaxf(cnt[g], 1.0f);
    float emb[32];
#pragma unroll
    for (int c = 0; c < 32; ++c) emb[c] = sums[g * 32 + c] * inv;
    float o = bc2[0];
#pragma unroll
    for (int j = 0; j < 16; ++j) {
        float h = bc1[j];
#pragma unroll
        for (int c = 0; c < 32; ++c) h += emb[c] * Wc1[c * 16 + j];
        o += fmaxf(h, 0.f) * Wc2[j];
    }
    out[g] = o;
}

extern "C" void kernel_launch(void* const* d_in, const int* in_sizes, int n_in,
                              void* d_out, int out_size, void* d_ws, size_t ws_size,
                              hipStream_t stream) {
    const float* x   = (const float*)d_in[0];
    const int*   ei  = (const int*)d_in[1];     // [2, E] flat: first E = src, next E = dst
    const int*   bat = (const int*)d_in[2];
    const float* W1  = (const float*)d_in[3];
    const float* b1  = (const float*)d_in[4];
    const float* W2  = (const float*)d_in[5];
    const float* b2  = (const float*)d_in[6];
    const float* W3  = (const float*)d_in[7];
    const float* b3  = (const float*)d_in[8];
    const float* Wc1 = (const float*)d_in[9];
    const float* bc1 = (const float*)d_in[10];
    const float* Wc2 = (const float*)d_in[11];
    const float* bc2 = (const float*)d_in[12];
    float* out = (float*)d_out;

    char* ws = (char*)d_ws;
    const size_t BUF_BYTES = (size_t)N_NODES * 64 * sizeof(float);  // 51.2 MB
    float* dis  = (float*)ws;                                  // N floats
    float* bufA = (float*)(ws + (1 << 20));
    float* bufB = (float*)(ws + (1 << 20) + BUF_BYTES);
    float* sums = (float*)(ws + (1 << 20) + 2 * BUF_BYTES);    // 2048*32
    float* cnt  = sums + N_GRAPHS * 32;                        // 2048

    const int TB = 256;
    const int nblk  = (N_NODES + TB - 1) / TB;
    const int eblk  = (N_EDGES + TB - 1) / TB;

    // degree / normalization
    init_deg<<<nblk, TB, 0, stream>>>(dis);
    count_deg<<<eblk, TB, 0, stream>>>(ei, dis);
    finalize_deg<<<nblk, TB, 0, stream>>>(dis);

    // ---- layer 1: x[N,128] @ W1 -> bufA[N,64]; scatter -> bufB; relu
    gemm_kernel<128, 64><<<(N_NODES + 3) / 4, TB, 0, stream>>>(x, W1, bufA, N_NODES);
    hipMemsetAsync(bufB, 0, BUF_BYTES, stream);
    scatter_kernel<64><<<(N_EDGES * 64 + TB - 1) / TB, TB, 0, stream>>>(bufA, dis, ei, bufB);
    finalize_kernel<64><<<(N_NODES * 64 + TB - 1) / TB, TB, 0, stream>>>(bufB, bufA, dis, b1);

    // ---- layer 2: bufB[N,64] @ W2 -> bufA[N,64]; scatter -> bufB; relu
    gemm_kernel<64, 64><<<(N_NODES + 3) / 4, TB, 0, stream>>>(bufB, W2, bufA, N_NODES);
    hipMemsetAsync(bufB, 0, BUF_BYTES, stream);
    scatter_kernel<64><<<(N_EDGES * 64 + TB - 1) / TB, TB, 0, stream>>>(bufA, dis, ei, bufB);
    finalize_kernel<64><<<(N_NODES * 64 + TB - 1) / TB, TB, 0, stream>>>(bufB, bufA, dis, b2);

    // ---- layer 3: bufB[N,64] @ W3 -> bufA[N,32]; scatter -> bufB; relu
    gemm_kernel<64, 32><<<(N_NODES + 7) / 8, TB, 0, stream>>>(bufB, W3, bufA, N_NODES);
    hipMemsetAsync(bufB, 0, (size_t)N_NODES * 32 * sizeof(float), stream);
    scatter_kernel<32><<<(N_EDGES * 32 + TB - 1) / TB, TB, 0, stream>>>(bufA, dis, ei, bufB);
    finalize_kernel<32><<<(N_NODES * 32 + TB - 1) / TB, TB, 0, stream>>>(bufB, bufA, dis, b3);

    // ---- pooling + classifier
    hipMemsetAsync(sums, 0, (size_t)(N_GRAPHS * 32 + N_GRAPHS) * sizeof(float), stream);
    pool_kernel<<<(N_NODES * 32 + TB - 1) / TB, TB, 0, stream>>>(bufB, bat, sums, cnt);
    classifier_kernel<<<(N_GRAPHS + TB - 1) / TB, TB, 0, stream>>>(sums, cnt, Wc1, bc1, Wc2, bc2, out);
}